// Round 1
// baseline (193.381 us; speedup 1.0000x reference)
//
#include <hip/hip_runtime.h>
#include <hip/hip_bf16.h>

// Ensemble MLP: E=8, B=16384, DS=32, DA=8, H=128, din=40 (padded to 64 for K).
// preds[i,j,b,:] = MLP_j(inp[i,b,:]); out0 = mean_i(preds)+states, out1 = var_i(preds, ddof=1)
//
// R9 = R8 + occupancy 3->4 blocks/CU:
// (a) __launch_bounds__(256,4): 4 blocks/CU (16 waves/CU = 4/SIMD). LDS is
//     exactly 4 x 40960 = 163840 B = 160 KiB/CU, VGPR 80 < 128 cap -> fits.
//     R8 counters showed no pipe saturated (MFMA 27% / VALU 52% / LDS ~50% /
//     HBM 17%) with Occupancy 29.5% -> latency/overlap-bound; a 4th
//     independent block per CU overlaps the serial MFMA->VALU->LDS->barrier
//     chains.
// (b) NSLOT 96 -> 128: grid = 1024 = 4/CU x 256, one generation, and
//     256 bt-tiles / 128 slots = exactly 2 tiles/block (R8's 2.67 gave ~11%
//     tail imbalance).
// Kept from R8: persistent blocks with resident weight fragments,
// bias-as-acc-init, XOR-swizzled unpadded LDS (40960 B), vectorized
// dwordx4+cvt_pk staging, weights-as-A for L0/L1 with packed b64 hidden
// stores, R4-orientation L2, deferred b2 algebra, race-safe prologue ordering.

#define NE 8
#define NB 16384
#define DS 32
#define DA 8
#define HH 128
#define DIN 40
#define BT 64            // batch rows per block-tile
#define NSLOT 128        // bt slots (grid = 8*NSLOT = 1024)
#define SLOPE 0.01f

using bf16x8 = __attribute__((ext_vector_type(8))) short;
using f32x4  = __attribute__((ext_vector_type(4))) float;

__device__ __forceinline__ unsigned short f2bf(float f) {
    unsigned int u = __float_as_uint(f);
    u += 0x7FFFu + ((u >> 16) & 1u);
    return (unsigned short)(u >> 16);
}

__device__ __forceinline__ float lrelu(float x) { return fmaxf(x, SLOPE * x); }

__device__ __forceinline__ unsigned int pack2bf(float a, float b) {
    union { __hip_bfloat162 h; unsigned int u; } cv;
    cv.h = __float22bfloat162_rn(make_float2(a, b));   // a -> low 16, b -> high 16
    return cv.u;
}

// Swizzled element indices (16B blocks of 8 bf16; block' = block ^ row-bits)
__device__ __forceinline__ int sin_idx(int row, int kb) {          // 64 elts/row
    return row * 64 + ((kb ^ (row & 7)) << 3);
}
__device__ __forceinline__ int sh_idx(int row, int kb) {           // 128 elts/row
    return row * 128 + ((kb ^ (row & 15)) << 3);
}

__global__ __launch_bounds__(256, 4)
void ens_mlp_kernel(const float* __restrict__ states,
                    const float* __restrict__ actions,
                    const float* __restrict__ W0g,
                    const float* __restrict__ b0g,
                    const float* __restrict__ W1g,
                    const float* __restrict__ b1g,
                    const float* __restrict__ W2g,
                    const float* __restrict__ b2g,
                    float* __restrict__ out)
{
    __shared__ __align__(16) unsigned short sIn[BT * 64];     //  8 KB
    __shared__ __align__(16) unsigned short sHa[BT * 128];    // 16 KB
    __shared__ __align__(16) unsigned short sHb[BT * 128];    // 16 KB  -> 40960 total

    const int j    = blockIdx.x & 7;          // j fast-varying
    const int slot = blockIdx.x >> 3;         // 0..127
    const int tid  = threadIdx.x;
    const int wave = tid >> 6;
    const int lane = tid & 63;
    const int q    = lane >> 4;
    const int l16  = lane & 15;
    const int fb   = 32 * wave;               // L0/L1: wave owns features fb..fb+31 (A/M dim)
    const int l2m  = 32 * (wave >> 1);        // L2 (R4 orientation): rows l2m..l2m+31
    const int l2n  = 16 * (wave & 1);         //                      cols l2n..l2n+15

    // zero-fill sIn once (swizzle-invariant); blocks 5..7 stay zero forever
    // (staging only writes blocks 0..4) = K padding cols 40..63.
    {
        uint4 z; z.x = z.y = z.z = z.w = 0u;
        uint4* p = reinterpret_cast<uint4*>(&sIn[tid * 32]);
        p[0] = z; p[1] = z; p[2] = z; p[3] = z;
    }

    const float* W0j = W0g + j * (DIN * HH);
    const float* W1j = W1g + j * (HH * HH);
    const float* W2j = W2g + j * (HH * DS);

    // ---- L0/L1 weight A-fragments: lane holds W[k = ks*32+q*8+t][feat = base+l16]
    bf16x8 w0f[2][2];   // 16 VGPRs (k >= 40 rows zero)
    bf16x8 w1f[4][2];   // 32 VGPRs
    bf16x8 w2f[4];      // 16 VGPRs (L2 B-frags, R4 orientation)
    f32x4 b0v[2], b1v[2];   // acc-init biases, C-layout (lane owns feats q*4+r)
    float b2s;

    #pragma unroll
    for (int ks = 0; ks < 2; ++ks)
      #pragma unroll
      for (int mt = 0; mt < 2; ++mt) {
        const int n = fb + mt * 16 + l16;
        #pragma unroll
        for (int t = 0; t < 8; ++t) {
          const int k = ks * 32 + q * 8 + t;
          w0f[ks][mt][t] = (short)((k < DIN) ? f2bf(W0j[k * HH + n]) : 0);
        }
      }
    #pragma unroll
    for (int ks = 0; ks < 4; ++ks)
      #pragma unroll
      for (int mt = 0; mt < 2; ++mt) {
        const int n = fb + mt * 16 + l16;
        #pragma unroll
        for (int t = 0; t < 8; ++t) {
          const int k = ks * 32 + q * 8 + t;
          w1f[ks][mt][t] = (short)f2bf(W1j[k * HH + n]);
        }
      }
    #pragma unroll
    for (int ks = 0; ks < 4; ++ks) {
        const int n = l2n + l16;
        #pragma unroll
        for (int t = 0; t < 8; ++t) {
          const int k = ks * 32 + q * 8 + t;
          w2f[ks][t] = (short)f2bf(W2j[k * DS + n]);
        }
    }
    #pragma unroll
    for (int mt = 0; mt < 2; ++mt)
      #pragma unroll
      for (int r = 0; r < 4; ++r) {
        b0v[mt][r] = b0g[j * HH + fb + mt * 16 + q * 4 + r];
        b1v[mt][r] = b1g[j * HH + fb + mt * 16 + q * 4 + r];
      }
    b2s = b2g[j * DS + l2n + l16];

    const f32x4 z4 = {0.f, 0.f, 0.f, 0.f};

    // staging geometry (constant across i and bt)
    const int srow = tid >> 2;        // states: row 0..63
    const int scb  = tid & 3;         // states: k-block 0..3
    const int soff = srow * DS + scb * 8;          // f32 offset within slice
    unsigned short* const sdst = &sIn[sin_idx(srow, scb)];
    unsigned short* const adst = &sIn[sin_idx(lane, 4)];   // wave 0 only

    for (int bt = slot; bt < NB / BT; bt += NSLOT) {
        const int b0 = bt * BT;

        // ---- stage inp[0] (vectorized). Safe: last sIn reads of the previous
        // bt (L0 i=7) completed before its B2; epilogue touches no LDS.
        // First bt: zero-fill above is pre-barrier for waves... all waves wrote
        // their own quarter; barrier below publishes everything before L0 reads.
        {
            const float4* sp = reinterpret_cast<const float4*>(
                states + (size_t)b0 * DS + soff);
            const float4 f0 = sp[0], f1 = sp[1];
            uint4 pk;
            pk.x = pack2bf(f0.x, f0.y); pk.y = pack2bf(f0.z, f0.w);
            pk.z = pack2bf(f1.x, f1.y); pk.w = pack2bf(f1.z, f1.w);
            *reinterpret_cast<uint4*>(sdst) = pk;
            if (tid < BT) {
                const float4* ap = reinterpret_cast<const float4*>(
                    actions + ((size_t)b0 + lane) * DA);
                const float4 a0 = ap[0], a1 = ap[1];
                uint4 apk;
                apk.x = pack2bf(a0.x, a0.y); apk.y = pack2bf(a0.z, a0.w);
                apk.z = pack2bf(a1.x, a1.y); apk.w = pack2bf(a1.z, a1.w);
                *reinterpret_cast<uint4*>(adst) = apk;
            }
        }
        __syncthreads();

        float sa[2][4], sq[2][4];
        #pragma unroll
        for (int mt = 0; mt < 2; ++mt)
          #pragma unroll
          for (int r = 0; r < 4; ++r) { sa[mt][r] = 0.f; sq[mt][r] = 0.f; }

        for (int i = 0; i < NE; ++i) {
            // ---- Layer 0: h0 = lrelu(W0^T inp + b0); acc init = b0 ----
            #pragma unroll
            for (int nh = 0; nh < 2; ++nh) {          // batch halves
                f32x4 acc[2][2];
                #pragma unroll
                for (int mt = 0; mt < 2; ++mt)
                  #pragma unroll
                  for (int nt = 0; nt < 2; ++nt) acc[mt][nt] = b0v[mt];
                #pragma unroll
                for (int ks = 0; ks < 2; ++ks) {
                    bf16x8 bf[2];
                    #pragma unroll
                    for (int nt = 0; nt < 2; ++nt) {
                        const int row = nh * 32 + nt * 16 + l16;   // B: n = lane&15
                        bf[nt] = *(const bf16x8*)(&sIn[sin_idx(row, ks * 4 + q)]);
                    }
                    #pragma unroll
                    for (int mt = 0; mt < 2; ++mt)
                      #pragma unroll
                      for (int nt = 0; nt < 2; ++nt)
                        acc[mt][nt] = __builtin_amdgcn_mfma_f32_16x16x32_bf16(
                            w0f[ks][mt], bf[nt], acc[mt][nt], 0, 0, 0);
                }
                // lane holds 4 consecutive features (q*4+r) of batch row nt*16+l16
                #pragma unroll
                for (int mt = 0; mt < 2; ++mt)
                  #pragma unroll
                  for (int nt = 0; nt < 2; ++nt) {
                    const int row = nh * 32 + nt * 16 + l16;
                    const int blk = (fb >> 3) + mt * 2 + (q >> 1);
                    const int idx = sh_idx(row, blk) + (q & 1) * 4;
                    const float v0 = lrelu(acc[mt][nt][0]);
                    const float v1 = lrelu(acc[mt][nt][1]);
                    const float v2 = lrelu(acc[mt][nt][2]);
                    const float v3 = lrelu(acc[mt][nt][3]);
                    uint2 pk; pk.x = pack2bf(v0, v1); pk.y = pack2bf(v2, v3);
                    *reinterpret_cast<uint2*>(&sHa[idx]) = pk;
                  }
            }
            __syncthreads();   // B2: h0 ready; sIn reads drained

            // ---- stage inp[i+1] (overlaps L1; writes blocks 0..4 only) ----
            if (i < NE - 1) {
                const float4* sp = reinterpret_cast<const float4*>(
                    states + ((size_t)(i + 1) * NB + b0) * DS + soff);
                const float4 f0 = sp[0], f1 = sp[1];
                uint4 pk;
                pk.x = pack2bf(f0.x, f0.y); pk.y = pack2bf(f0.z, f0.w);
                pk.z = pack2bf(f1.x, f1.y); pk.w = pack2bf(f1.z, f1.w);
                *reinterpret_cast<uint4*>(sdst) = pk;
                if (tid < BT) {
                    const float4* ap = reinterpret_cast<const float4*>(
                        actions + ((size_t)(i + 1) * NB + b0 + lane) * DA);
                    const float4 a0 = ap[0], a1 = ap[1];
                    uint4 apk;
                    apk.x = pack2bf(a0.x, a0.y); apk.y = pack2bf(a0.z, a0.w);
                    apk.z = pack2bf(a1.x, a1.y); apk.w = pack2bf(a1.z, a1.w);
                    *reinterpret_cast<uint4*>(adst) = apk;
                }
            }

            // ---- Layer 1: h1 = lrelu(W1^T h0 + b1); acc init = b1 ----
            #pragma unroll
            for (int nh = 0; nh < 2; ++nh) {
                f32x4 acc[2][2];
                #pragma unroll
                for (int mt = 0; mt < 2; ++mt)
                  #pragma unroll
                  for (int nt = 0; nt < 2; ++nt) acc[mt][nt] = b1v[mt];
                #pragma unroll
                for (int ks = 0; ks < 4; ++ks) {
                    bf16x8 bf[2];
                    #pragma unroll
                    for (int nt = 0; nt < 2; ++nt) {
                        const int row = nh * 32 + nt * 16 + l16;
                        bf[nt] = *(const bf16x8*)(&sHa[sh_idx(row, ks * 4 + q)]);
                    }
                    #pragma unroll
                    for (int mt = 0; mt < 2; ++mt)
                      #pragma unroll
                      for (int nt = 0; nt < 2; ++nt)
                        acc[mt][nt] = __builtin_amdgcn_mfma_f32_16x16x32_bf16(
                            w1f[ks][mt], bf[nt], acc[mt][nt], 0, 0, 0);
                }
                #pragma unroll
                for (int mt = 0; mt < 2; ++mt)
                  #pragma unroll
                  for (int nt = 0; nt < 2; ++nt) {
                    const int row = nh * 32 + nt * 16 + l16;
                    const int blk = (fb >> 3) + mt * 2 + (q >> 1);
                    const int idx = sh_idx(row, blk) + (q & 1) * 4;
                    const float v0 = lrelu(acc[mt][nt][0]);
                    const float v1 = lrelu(acc[mt][nt][1]);
                    const float v2 = lrelu(acc[mt][nt][2]);
                    const float v3 = lrelu(acc[mt][nt][3]);
                    uint2 pk; pk.x = pack2bf(v0, v1); pk.y = pack2bf(v2, v3);
                    *reinterpret_cast<uint2*>(&sHb[idx]) = pk;
                  }
            }
            __syncthreads();   // B3: h1 + sIn(i+1) ready

            // ---- Layer 2 (R4 orientation): A=h1 (m=batch), B=W2 (n=feature) ----
            {
                f32x4 acc2[2];
                acc2[0] = z4; acc2[1] = z4;
                #pragma unroll
                for (int ks = 0; ks < 4; ++ks) {
                    #pragma unroll
                    for (int mt = 0; mt < 2; ++mt) {
                        const int row = l2m + 16 * mt + l16;
                        const bf16x8 a2 = *(const bf16x8*)(&sHb[sh_idx(row, ks * 4 + q)]);
                        acc2[mt] = __builtin_amdgcn_mfma_f32_16x16x32_bf16(
                            a2, w2f[ks], acc2[mt], 0, 0, 0);
                    }
                }
                #pragma unroll
                for (int mt = 0; mt < 2; ++mt)
                  #pragma unroll
                  for (int r = 0; r < 4; ++r) {
                    const float a = acc2[mt][r];      // b2 deferred
                    sa[mt][r] += a;
                    sq[mt][r] = fmaf(a, a, sq[mt][r]);
                  }
            }
        }

        // ---- Epilogue for this bt: sum = sa + 8b; sum(p^2) = sq + 2b*sa + 8b^2
        #pragma unroll
        for (int mt = 0; mt < 2; ++mt)
          #pragma unroll
          for (int r = 0; r < 4; ++r) {
            const int row = l2m + 16 * mt + q * 4 + r;   // batch row (C: row=quad*4+r)
            const int col = l2n + l16;                   // feature
            const size_t o = ((size_t)j * NB + b0 + row) * DS + col;
            const float b  = b2s;
            const float s  = sa[mt][r] + 8.f * b;
            const float s2 = sq[mt][r] + 2.f * b * sa[mt][r] + 8.f * b * b;
            out[o] = s * 0.125f + states[o];
            out[(size_t)NE * NB * DS + o] = (s2 - s * s * 0.125f) * (1.0f / 7.0f);
          }
    }
}

extern "C" void kernel_launch(void* const* d_in, const int* in_sizes, int n_in,
                              void* d_out, int out_size, void* d_ws, size_t ws_size,
                              hipStream_t stream) {
    (void)in_sizes; (void)n_in; (void)d_ws; (void)ws_size; (void)out_size;
    const float* states  = (const float*)d_in[0];
    const float* actions = (const float*)d_in[1];
    const float* W0 = (const float*)d_in[2];
    const float* b0 = (const float*)d_in[3];
    const float* W1 = (const float*)d_in[4];
    const float* b1 = (const float*)d_in[5];
    const float* W2 = (const float*)d_in[6];
    const float* b2 = (const float*)d_in[7];
    float* out = (float*)d_out;
    dim3 grid(8 * NSLOT);   // 1024 persistent blocks = 4/CU, one generation, 2 bt-tiles each
    ens_mlp_kernel<<<grid, dim3(256), 0, stream>>>(states, actions, W0, b0, W1, b1, W2, b2, out);
}

// Round 2
// 167.006 us; speedup vs baseline: 1.1579x; 1.1579x over previous
//
#include <hip/hip_runtime.h>
#include <hip/hip_bf16.h>

// Ensemble MLP: E=8, B=16384, DS=32, DA=8, H=128, din=40 (padded to 64 for K).
// preds[i,j,b,:] = MLP_j(inp[i,b,:]); out0 = mean_i(preds)+states, out1 = var_i(preds, ddof=1)
//
// R10 = R9 geometry with the VGPR squeeze removed:
// - grid = 1024 (4 blocks/CU, one generation, exactly 2 bt-tiles/block).
//   R9 proved 4 blocks/CU co-schedule (LDS 4x40960 = exactly 160 KiB,
//   Occupancy hit 40%).
// - __launch_bounds__(256,3) (NOT 4): R9's (256,4) capped VGPR at 64 and the
//   ~100-live-reg inner loop spilled to scratch (VGPR 80->64, FETCH 87->200 MB,
//   WRITE 33->65 MB = spill/fill signature). Per the 64/128/256 VGPR
//   occupancy granularity, an 80-VGPR wave already occupies a 128-reg slot,
//   so 4 waves/SIMD are reachable WITHOUT lowering the compiler cap.
// Kept from R8: persistent blocks with resident weight fragments,
// bias-as-acc-init, XOR-swizzled unpadded LDS (40960 B), vectorized
// dwordx4+cvt_pk staging, weights-as-A for L0/L1 with packed b64 hidden
// stores, R4-orientation L2, deferred b2 algebra, race-safe prologue ordering.

#define NE 8
#define NB 16384
#define DS 32
#define DA 8
#define HH 128
#define DIN 40
#define BT 64            // batch rows per block-tile
#define NSLOT 128        // bt slots (grid = 8*NSLOT = 1024)
#define SLOPE 0.01f

using bf16x8 = __attribute__((ext_vector_type(8))) short;
using f32x4  = __attribute__((ext_vector_type(4))) float;

__device__ __forceinline__ unsigned short f2bf(float f) {
    unsigned int u = __float_as_uint(f);
    u += 0x7FFFu + ((u >> 16) & 1u);
    return (unsigned short)(u >> 16);
}

__device__ __forceinline__ float lrelu(float x) { return fmaxf(x, SLOPE * x); }

__device__ __forceinline__ unsigned int pack2bf(float a, float b) {
    union { __hip_bfloat162 h; unsigned int u; } cv;
    cv.h = __float22bfloat162_rn(make_float2(a, b));   // a -> low 16, b -> high 16
    return cv.u;
}

// Swizzled element indices (16B blocks of 8 bf16; block' = block ^ row-bits)
__device__ __forceinline__ int sin_idx(int row, int kb) {          // 64 elts/row
    return row * 64 + ((kb ^ (row & 7)) << 3);
}
__device__ __forceinline__ int sh_idx(int row, int kb) {           // 128 elts/row
    return row * 128 + ((kb ^ (row & 15)) << 3);
}

__global__ __launch_bounds__(256, 3)
void ens_mlp_kernel(const float* __restrict__ states,
                    const float* __restrict__ actions,
                    const float* __restrict__ W0g,
                    const float* __restrict__ b0g,
                    const float* __restrict__ W1g,
                    const float* __restrict__ b1g,
                    const float* __restrict__ W2g,
                    const float* __restrict__ b2g,
                    float* __restrict__ out)
{
    __shared__ __align__(16) unsigned short sIn[BT * 64];     //  8 KB
    __shared__ __align__(16) unsigned short sHa[BT * 128];    // 16 KB
    __shared__ __align__(16) unsigned short sHb[BT * 128];    // 16 KB  -> 40960 total

    const int j    = blockIdx.x & 7;          // j fast-varying
    const int slot = blockIdx.x >> 3;         // 0..127
    const int tid  = threadIdx.x;
    const int wave = tid >> 6;
    const int lane = tid & 63;
    const int q    = lane >> 4;
    const int l16  = lane & 15;
    const int fb   = 32 * wave;               // L0/L1: wave owns features fb..fb+31 (A/M dim)
    const int l2m  = 32 * (wave >> 1);        // L2 (R4 orientation): rows l2m..l2m+31
    const int l2n  = 16 * (wave & 1);         //                      cols l2n..l2n+15

    // zero-fill sIn once (swizzle-invariant); blocks 5..7 stay zero forever
    // (staging only writes blocks 0..4) = K padding cols 40..63.
    {
        uint4 z; z.x = z.y = z.z = z.w = 0u;
        uint4* p = reinterpret_cast<uint4*>(&sIn[tid * 32]);
        p[0] = z; p[1] = z; p[2] = z; p[3] = z;
    }

    const float* W0j = W0g + j * (DIN * HH);
    const float* W1j = W1g + j * (HH * HH);
    const float* W2j = W2g + j * (HH * DS);

    // ---- L0/L1 weight A-fragments: lane holds W[k = ks*32+q*8+t][feat = base+l16]
    bf16x8 w0f[2][2];   // 16 VGPRs (k >= 40 rows zero)
    bf16x8 w1f[4][2];   // 32 VGPRs
    bf16x8 w2f[4];      // 16 VGPRs (L2 B-frags, R4 orientation)
    f32x4 b0v[2], b1v[2];   // acc-init biases, C-layout (lane owns feats q*4+r)
    float b2s;

    #pragma unroll
    for (int ks = 0; ks < 2; ++ks)
      #pragma unroll
      for (int mt = 0; mt < 2; ++mt) {
        const int n = fb + mt * 16 + l16;
        #pragma unroll
        for (int t = 0; t < 8; ++t) {
          const int k = ks * 32 + q * 8 + t;
          w0f[ks][mt][t] = (short)((k < DIN) ? f2bf(W0j[k * HH + n]) : 0);
        }
      }
    #pragma unroll
    for (int ks = 0; ks < 4; ++ks)
      #pragma unroll
      for (int mt = 0; mt < 2; ++mt) {
        const int n = fb + mt * 16 + l16;
        #pragma unroll
        for (int t = 0; t < 8; ++t) {
          const int k = ks * 32 + q * 8 + t;
          w1f[ks][mt][t] = (short)f2bf(W1j[k * HH + n]);
        }
      }
    #pragma unroll
    for (int ks = 0; ks < 4; ++ks) {
        const int n = l2n + l16;
        #pragma unroll
        for (int t = 0; t < 8; ++t) {
          const int k = ks * 32 + q * 8 + t;
          w2f[ks][t] = (short)f2bf(W2j[k * DS + n]);
        }
    }
    #pragma unroll
    for (int mt = 0; mt < 2; ++mt)
      #pragma unroll
      for (int r = 0; r < 4; ++r) {
        b0v[mt][r] = b0g[j * HH + fb + mt * 16 + q * 4 + r];
        b1v[mt][r] = b1g[j * HH + fb + mt * 16 + q * 4 + r];
      }
    b2s = b2g[j * DS + l2n + l16];

    const f32x4 z4 = {0.f, 0.f, 0.f, 0.f};

    // staging geometry (constant across i and bt)
    const int srow = tid >> 2;        // states: row 0..63
    const int scb  = tid & 3;         // states: k-block 0..3
    const int soff = srow * DS + scb * 8;          // f32 offset within slice
    unsigned short* const sdst = &sIn[sin_idx(srow, scb)];
    unsigned short* const adst = &sIn[sin_idx(lane, 4)];   // wave 0 only

    for (int bt = slot; bt < NB / BT; bt += NSLOT) {
        const int b0 = bt * BT;

        // ---- stage inp[0] (vectorized). Safe: last sIn reads of the previous
        // bt (L0 i=7) completed before its B2; epilogue touches no LDS.
        // First bt: zero-fill above is pre-barrier for waves... all waves wrote
        // their own quarter; barrier below publishes everything before L0 reads.
        {
            const float4* sp = reinterpret_cast<const float4*>(
                states + (size_t)b0 * DS + soff);
            const float4 f0 = sp[0], f1 = sp[1];
            uint4 pk;
            pk.x = pack2bf(f0.x, f0.y); pk.y = pack2bf(f0.z, f0.w);
            pk.z = pack2bf(f1.x, f1.y); pk.w = pack2bf(f1.z, f1.w);
            *reinterpret_cast<uint4*>(sdst) = pk;
            if (tid < BT) {
                const float4* ap = reinterpret_cast<const float4*>(
                    actions + ((size_t)b0 + lane) * DA);
                const float4 a0 = ap[0], a1 = ap[1];
                uint4 apk;
                apk.x = pack2bf(a0.x, a0.y); apk.y = pack2bf(a0.z, a0.w);
                apk.z = pack2bf(a1.x, a1.y); apk.w = pack2bf(a1.z, a1.w);
                *reinterpret_cast<uint4*>(adst) = apk;
            }
        }
        __syncthreads();

        float sa[2][4], sq[2][4];
        #pragma unroll
        for (int mt = 0; mt < 2; ++mt)
          #pragma unroll
          for (int r = 0; r < 4; ++r) { sa[mt][r] = 0.f; sq[mt][r] = 0.f; }

        for (int i = 0; i < NE; ++i) {
            // ---- Layer 0: h0 = lrelu(W0^T inp + b0); acc init = b0 ----
            #pragma unroll
            for (int nh = 0; nh < 2; ++nh) {          // batch halves
                f32x4 acc[2][2];
                #pragma unroll
                for (int mt = 0; mt < 2; ++mt)
                  #pragma unroll
                  for (int nt = 0; nt < 2; ++nt) acc[mt][nt] = b0v[mt];
                #pragma unroll
                for (int ks = 0; ks < 2; ++ks) {
                    bf16x8 bf[2];
                    #pragma unroll
                    for (int nt = 0; nt < 2; ++nt) {
                        const int row = nh * 32 + nt * 16 + l16;   // B: n = lane&15
                        bf[nt] = *(const bf16x8*)(&sIn[sin_idx(row, ks * 4 + q)]);
                    }
                    #pragma unroll
                    for (int mt = 0; mt < 2; ++mt)
                      #pragma unroll
                      for (int nt = 0; nt < 2; ++nt)
                        acc[mt][nt] = __builtin_amdgcn_mfma_f32_16x16x32_bf16(
                            w0f[ks][mt], bf[nt], acc[mt][nt], 0, 0, 0);
                }
                // lane holds 4 consecutive features (q*4+r) of batch row nt*16+l16
                #pragma unroll
                for (int mt = 0; mt < 2; ++mt)
                  #pragma unroll
                  for (int nt = 0; nt < 2; ++nt) {
                    const int row = nh * 32 + nt * 16 + l16;
                    const int blk = (fb >> 3) + mt * 2 + (q >> 1);
                    const int idx = sh_idx(row, blk) + (q & 1) * 4;
                    const float v0 = lrelu(acc[mt][nt][0]);
                    const float v1 = lrelu(acc[mt][nt][1]);
                    const float v2 = lrelu(acc[mt][nt][2]);
                    const float v3 = lrelu(acc[mt][nt][3]);
                    uint2 pk; pk.x = pack2bf(v0, v1); pk.y = pack2bf(v2, v3);
                    *reinterpret_cast<uint2*>(&sHa[idx]) = pk;
                  }
            }
            __syncthreads();   // B2: h0 ready; sIn reads drained

            // ---- stage inp[i+1] (overlaps L1; writes blocks 0..4 only) ----
            if (i < NE - 1) {
                const float4* sp = reinterpret_cast<const float4*>(
                    states + ((size_t)(i + 1) * NB + b0) * DS + soff);
                const float4 f0 = sp[0], f1 = sp[1];
                uint4 pk;
                pk.x = pack2bf(f0.x, f0.y); pk.y = pack2bf(f0.z, f0.w);
                pk.z = pack2bf(f1.x, f1.y); pk.w = pack2bf(f1.z, f1.w);
                *reinterpret_cast<uint4*>(sdst) = pk;
                if (tid < BT) {
                    const float4* ap = reinterpret_cast<const float4*>(
                        actions + ((size_t)(i + 1) * NB + b0 + lane) * DA);
                    const float4 a0 = ap[0], a1 = ap[1];
                    uint4 apk;
                    apk.x = pack2bf(a0.x, a0.y); apk.y = pack2bf(a0.z, a0.w);
                    apk.z = pack2bf(a1.x, a1.y); apk.w = pack2bf(a1.z, a1.w);
                    *reinterpret_cast<uint4*>(adst) = apk;
                }
            }

            // ---- Layer 1: h1 = lrelu(W1^T h0 + b1); acc init = b1 ----
            #pragma unroll
            for (int nh = 0; nh < 2; ++nh) {
                f32x4 acc[2][2];
                #pragma unroll
                for (int mt = 0; mt < 2; ++mt)
                  #pragma unroll
                  for (int nt = 0; nt < 2; ++nt) acc[mt][nt] = b1v[mt];
                #pragma unroll
                for (int ks = 0; ks < 4; ++ks) {
                    bf16x8 bf[2];
                    #pragma unroll
                    for (int nt = 0; nt < 2; ++nt) {
                        const int row = nh * 32 + nt * 16 + l16;
                        bf[nt] = *(const bf16x8*)(&sHa[sh_idx(row, ks * 4 + q)]);
                    }
                    #pragma unroll
                    for (int mt = 0; mt < 2; ++mt)
                      #pragma unroll
                      for (int nt = 0; nt < 2; ++nt)
                        acc[mt][nt] = __builtin_amdgcn_mfma_f32_16x16x32_bf16(
                            w1f[ks][mt], bf[nt], acc[mt][nt], 0, 0, 0);
                }
                #pragma unroll
                for (int mt = 0; mt < 2; ++mt)
                  #pragma unroll
                  for (int nt = 0; nt < 2; ++nt) {
                    const int row = nh * 32 + nt * 16 + l16;
                    const int blk = (fb >> 3) + mt * 2 + (q >> 1);
                    const int idx = sh_idx(row, blk) + (q & 1) * 4;
                    const float v0 = lrelu(acc[mt][nt][0]);
                    const float v1 = lrelu(acc[mt][nt][1]);
                    const float v2 = lrelu(acc[mt][nt][2]);
                    const float v3 = lrelu(acc[mt][nt][3]);
                    uint2 pk; pk.x = pack2bf(v0, v1); pk.y = pack2bf(v2, v3);
                    *reinterpret_cast<uint2*>(&sHb[idx]) = pk;
                  }
            }
            __syncthreads();   // B3: h1 + sIn(i+1) ready

            // ---- Layer 2 (R4 orientation): A=h1 (m=batch), B=W2 (n=feature) ----
            {
                f32x4 acc2[2];
                acc2[0] = z4; acc2[1] = z4;
                #pragma unroll
                for (int ks = 0; ks < 4; ++ks) {
                    #pragma unroll
                    for (int mt = 0; mt < 2; ++mt) {
                        const int row = l2m + 16 * mt + l16;
                        const bf16x8 a2 = *(const bf16x8*)(&sHb[sh_idx(row, ks * 4 + q)]);
                        acc2[mt] = __builtin_amdgcn_mfma_f32_16x16x32_bf16(
                            a2, w2f[ks], acc2[mt], 0, 0, 0);
                    }
                }
                #pragma unroll
                for (int mt = 0; mt < 2; ++mt)
                  #pragma unroll
                  for (int r = 0; r < 4; ++r) {
                    const float a = acc2[mt][r];      // b2 deferred
                    sa[mt][r] += a;
                    sq[mt][r] = fmaf(a, a, sq[mt][r]);
                  }
            }
        }

        // ---- Epilogue for this bt: sum = sa + 8b; sum(p^2) = sq + 2b*sa + 8b^2
        #pragma unroll
        for (int mt = 0; mt < 2; ++mt)
          #pragma unroll
          for (int r = 0; r < 4; ++r) {
            const int row = l2m + 16 * mt + q * 4 + r;   // batch row (C: row=quad*4+r)
            const int col = l2n + l16;                   // feature
            const size_t o = ((size_t)j * NB + b0 + row) * DS + col;
            const float b  = b2s;
            const float s  = sa[mt][r] + 8.f * b;
            const float s2 = sq[mt][r] + 2.f * b * sa[mt][r] + 8.f * b * b;
            out[o] = s * 0.125f + states[o];
            out[(size_t)NE * NB * DS + o] = (s2 - s * s * 0.125f) * (1.0f / 7.0f);
          }
    }
}

extern "C" void kernel_launch(void* const* d_in, const int* in_sizes, int n_in,
                              void* d_out, int out_size, void* d_ws, size_t ws_size,
                              hipStream_t stream) {
    (void)in_sizes; (void)n_in; (void)d_ws; (void)ws_size; (void)out_size;
    const float* states  = (const float*)d_in[0];
    const float* actions = (const float*)d_in[1];
    const float* W0 = (const float*)d_in[2];
    const float* b0 = (const float*)d_in[3];
    const float* W1 = (const float*)d_in[4];
    const float* b1 = (const float*)d_in[5];
    const float* W2 = (const float*)d_in[6];
    const float* b2 = (const float*)d_in[7];
    float* out = (float*)d_out;
    dim3 grid(8 * NSLOT);   // 1024 blocks = 4/CU (LDS exactly 4x40960=160KiB), one generation
    ens_mlp_kernel<<<grid, dim3(256), 0, stream>>>(states, actions, W0, b0, W1, b1, W2, b2, out);
}

// Round 4
// 145.401 us; speedup vs baseline: 1.3300x; 1.1486x over previous
//
#include <hip/hip_runtime.h>
#include <hip/hip_fp16.h>

// Ensemble MLP: E=8, B=16384, DS=32, DA=8, H=128, din=40 (padded to 64 for K).
// preds[i,j,b,:] = MLP_j(inp[i,b,:]); out0 = mean_i(preds)+states, out1 = var_i(preds, ddof=1)
//
// R12 = R11 with the cvt_pkrtz type fix (builtin returns __fp16x2 on this
// ROCm; bit-cast to _Float16x2 before packed math).
// R11 theory: R8 geometry (grid 768 = 3 blocks/CU, one generation -- R9/R10
// proved 4/CU needs VGPR<=64 which forces spills; 80-VGPR kernels cap at
// 3/CU) with the datapath switched bf16 -> f16 and PACKED leaky-relu:
// - v_cvt_pkrtz_f16_f32 (1 op / 2 elems) + v_pk_mul_f16 + v_pk_max_f16
//   = 3 VALU per 2 elements vs 5 for the bf16 path.
//   R8 showed VALUBusy ~50% as top pipe; epilogue lrelu+pack dominated.
//   Predicted VALUBusy -> ~40%, dur 90 -> ~80.
// - mfma_f32_16x16x32_f16: same rate, same fragment/C layout as bf16.
// - Precision improves (f16: 10 mantissa bits vs bf16: 8).
// Kept from R8: persistent blocks with resident weight fragments,
// bias-as-acc-init, XOR-swizzled unpadded LDS (40960 B), vectorized
// dwordx4 staging, weights-as-A for L0/L1 with packed b64 hidden stores,
// R4-orientation L2, deferred b2 algebra, race-safe prologue ordering.

#define NE 8
#define NB 16384
#define DS 32
#define DA 8
#define HH 128
#define DIN 40
#define BT 64            // batch rows per block-tile
#define NSLOT 96         // bt slots (grid = 8*NSLOT = 768 = 3/CU)
#define SLOPE 0.01f

using h16x8 = __attribute__((ext_vector_type(8))) _Float16;
using f16x2 = __attribute__((ext_vector_type(2))) _Float16;
using f32x4 = __attribute__((ext_vector_type(4))) float;

// cvt_pkrtz returns ext_vector(2) of __fp16 on this toolchain; bit-cast to
// _Float16x2 so subsequent arithmetic stays packed (no float promotion).
__device__ __forceinline__ f16x2 cvtpk(float a, float b) {
    auto r = __builtin_amdgcn_cvt_pkrtz(a, b);
    union { decltype(r) i; f16x2 o; } cv; cv.i = r; return cv.o;
}

// pack 2 f32 -> 2 f16 (RTZ), no activation (staging)
__device__ __forceinline__ unsigned int pkh(float a, float b) {
    union { f16x2 h; unsigned int u; } cv;
    cv.h = cvtpk(a, b);
    return cv.u;
}

// pack 2 f32 -> 2 f16 with packed leaky-relu: cvt_pkrtz + pk_mul + pk_max
__device__ __forceinline__ unsigned int pklr(float a, float b) {
    f16x2 z = cvtpk(a, b);
    f16x2 s = z * (_Float16)SLOPE;              // v_pk_mul_f16
    f16x2 r = __builtin_elementwise_max(z, s);  // v_pk_max_f16
    union { f16x2 h; unsigned int u; } cv; cv.h = r; return cv.u;
}

// Swizzled element indices (16B blocks of 8 f16; block' = block ^ row-bits)
__device__ __forceinline__ int sin_idx(int row, int kb) {          // 64 elts/row
    return row * 64 + ((kb ^ (row & 7)) << 3);
}
__device__ __forceinline__ int sh_idx(int row, int kb) {           // 128 elts/row
    return row * 128 + ((kb ^ (row & 15)) << 3);
}

__global__ __launch_bounds__(256, 3)
void ens_mlp_kernel(const float* __restrict__ states,
                    const float* __restrict__ actions,
                    const float* __restrict__ W0g,
                    const float* __restrict__ b0g,
                    const float* __restrict__ W1g,
                    const float* __restrict__ b1g,
                    const float* __restrict__ W2g,
                    const float* __restrict__ b2g,
                    float* __restrict__ out)
{
    __shared__ __align__(16) unsigned short sIn[BT * 64];     //  8 KB
    __shared__ __align__(16) unsigned short sHa[BT * 128];    // 16 KB
    __shared__ __align__(16) unsigned short sHb[BT * 128];    // 16 KB  -> 40960 total

    const int j    = blockIdx.x & 7;          // j fast-varying
    const int slot = blockIdx.x >> 3;         // 0..95
    const int tid  = threadIdx.x;
    const int wave = tid >> 6;
    const int lane = tid & 63;
    const int q    = lane >> 4;
    const int l16  = lane & 15;
    const int fb   = 32 * wave;               // L0/L1: wave owns features fb..fb+31 (A/M dim)
    const int l2m  = 32 * (wave >> 1);        // L2 (R4 orientation): rows l2m..l2m+31
    const int l2n  = 16 * (wave & 1);         //                      cols l2n..l2n+15

    // zero-fill sIn once (swizzle-invariant); blocks 5..7 stay zero forever
    // (staging only writes blocks 0..4) = K padding cols 40..63.
    {
        uint4 z; z.x = z.y = z.z = z.w = 0u;
        uint4* p = reinterpret_cast<uint4*>(&sIn[tid * 32]);
        p[0] = z; p[1] = z; p[2] = z; p[3] = z;
    }

    const float* W0j = W0g + j * (DIN * HH);
    const float* W1j = W1g + j * (HH * HH);
    const float* W2j = W2g + j * (HH * DS);

    // ---- L0/L1 weight A-fragments: lane holds W[k = ks*32+q*8+t][feat = base+l16]
    h16x8 w0f[2][2];   // 16 VGPRs (k >= 40 rows zero)
    h16x8 w1f[4][2];   // 32 VGPRs
    h16x8 w2f[4];      // 16 VGPRs (L2 B-frags, R4 orientation)
    f32x4 b0v[2], b1v[2];   // acc-init biases, C-layout (lane owns feats q*4+r)
    float b2s;

    #pragma unroll
    for (int ks = 0; ks < 2; ++ks)
      #pragma unroll
      for (int mt = 0; mt < 2; ++mt) {
        const int n = fb + mt * 16 + l16;
        #pragma unroll
        for (int t = 0; t < 8; ++t) {
          const int k = ks * 32 + q * 8 + t;
          w0f[ks][mt][t] = (_Float16)((k < DIN) ? W0j[k * HH + n] : 0.f);
        }
      }
    #pragma unroll
    for (int ks = 0; ks < 4; ++ks)
      #pragma unroll
      for (int mt = 0; mt < 2; ++mt) {
        const int n = fb + mt * 16 + l16;
        #pragma unroll
        for (int t = 0; t < 8; ++t) {
          const int k = ks * 32 + q * 8 + t;
          w1f[ks][mt][t] = (_Float16)W1j[k * HH + n];
        }
      }
    #pragma unroll
    for (int ks = 0; ks < 4; ++ks) {
        const int n = l2n + l16;
        #pragma unroll
        for (int t = 0; t < 8; ++t) {
          const int k = ks * 32 + q * 8 + t;
          w2f[ks][t] = (_Float16)W2j[k * DS + n];
        }
    }
    #pragma unroll
    for (int mt = 0; mt < 2; ++mt)
      #pragma unroll
      for (int r = 0; r < 4; ++r) {
        b0v[mt][r] = b0g[j * HH + fb + mt * 16 + q * 4 + r];
        b1v[mt][r] = b1g[j * HH + fb + mt * 16 + q * 4 + r];
      }
    b2s = b2g[j * DS + l2n + l16];

    const f32x4 z4 = {0.f, 0.f, 0.f, 0.f};

    // staging geometry (constant across i and bt)
    const int srow = tid >> 2;        // states: row 0..63
    const int scb  = tid & 3;         // states: k-block 0..3
    const int soff = srow * DS + scb * 8;          // f32 offset within slice
    unsigned short* const sdst = &sIn[sin_idx(srow, scb)];
    unsigned short* const adst = &sIn[sin_idx(lane, 4)];   // wave 0 only

    for (int bt = slot; bt < NB / BT; bt += NSLOT) {
        const int b0 = bt * BT;

        // ---- stage inp[0] (vectorized). Safe: last sIn reads of the previous
        // bt (L0 i=7) completed before its B2; epilogue touches no LDS.
        {
            const float4* sp = reinterpret_cast<const float4*>(
                states + (size_t)b0 * DS + soff);
            const float4 f0 = sp[0], f1 = sp[1];
            uint4 pk;
            pk.x = pkh(f0.x, f0.y); pk.y = pkh(f0.z, f0.w);
            pk.z = pkh(f1.x, f1.y); pk.w = pkh(f1.z, f1.w);
            *reinterpret_cast<uint4*>(sdst) = pk;
            if (tid < BT) {
                const float4* ap = reinterpret_cast<const float4*>(
                    actions + ((size_t)b0 + lane) * DA);
                const float4 a0 = ap[0], a1 = ap[1];
                uint4 apk;
                apk.x = pkh(a0.x, a0.y); apk.y = pkh(a0.z, a0.w);
                apk.z = pkh(a1.x, a1.y); apk.w = pkh(a1.z, a1.w);
                *reinterpret_cast<uint4*>(adst) = apk;
            }
        }
        __syncthreads();

        float sa[2][4], sq[2][4];
        #pragma unroll
        for (int mt = 0; mt < 2; ++mt)
          #pragma unroll
          for (int r = 0; r < 4; ++r) { sa[mt][r] = 0.f; sq[mt][r] = 0.f; }

        for (int i = 0; i < NE; ++i) {
            // ---- Layer 0: h0 = lrelu(W0^T inp + b0); acc init = b0 ----
            #pragma unroll
            for (int nh = 0; nh < 2; ++nh) {          // batch halves
                f32x4 acc[2][2];
                #pragma unroll
                for (int mt = 0; mt < 2; ++mt)
                  #pragma unroll
                  for (int nt = 0; nt < 2; ++nt) acc[mt][nt] = b0v[mt];
                #pragma unroll
                for (int ks = 0; ks < 2; ++ks) {
                    h16x8 bf[2];
                    #pragma unroll
                    for (int nt = 0; nt < 2; ++nt) {
                        const int row = nh * 32 + nt * 16 + l16;   // B: n = lane&15
                        bf[nt] = *(const h16x8*)(&sIn[sin_idx(row, ks * 4 + q)]);
                    }
                    #pragma unroll
                    for (int mt = 0; mt < 2; ++mt)
                      #pragma unroll
                      for (int nt = 0; nt < 2; ++nt)
                        acc[mt][nt] = __builtin_amdgcn_mfma_f32_16x16x32_f16(
                            w0f[ks][mt], bf[nt], acc[mt][nt], 0, 0, 0);
                }
                // lane holds 4 consecutive features (q*4+r) of batch row nt*16+l16
                #pragma unroll
                for (int mt = 0; mt < 2; ++mt)
                  #pragma unroll
                  for (int nt = 0; nt < 2; ++nt) {
                    const int row = nh * 32 + nt * 16 + l16;
                    const int blk = (fb >> 3) + mt * 2 + (q >> 1);
                    const int idx = sh_idx(row, blk) + (q & 1) * 4;
                    uint2 pk;
                    pk.x = pklr(acc[mt][nt][0], acc[mt][nt][1]);
                    pk.y = pklr(acc[mt][nt][2], acc[mt][nt][3]);
                    *reinterpret_cast<uint2*>(&sHa[idx]) = pk;
                  }
            }
            __syncthreads();   // B2: h0 ready; sIn reads drained

            // ---- stage inp[i+1] (overlaps L1; writes blocks 0..4 only) ----
            if (i < NE - 1) {
                const float4* sp = reinterpret_cast<const float4*>(
                    states + ((size_t)(i + 1) * NB + b0) * DS + soff);
                const float4 f0 = sp[0], f1 = sp[1];
                uint4 pk;
                pk.x = pkh(f0.x, f0.y); pk.y = pkh(f0.z, f0.w);
                pk.z = pkh(f1.x, f1.y); pk.w = pkh(f1.z, f1.w);
                *reinterpret_cast<uint4*>(sdst) = pk;
                if (tid < BT) {
                    const float4* ap = reinterpret_cast<const float4*>(
                        actions + ((size_t)(i + 1) * NB + b0 + lane) * DA);
                    const float4 a0 = ap[0], a1 = ap[1];
                    uint4 apk;
                    apk.x = pkh(a0.x, a0.y); apk.y = pkh(a0.z, a0.w);
                    apk.z = pkh(a1.x, a1.y); apk.w = pkh(a1.z, a1.w);
                    *reinterpret_cast<uint4*>(adst) = apk;
                }
            }

            // ---- Layer 1: h1 = lrelu(W1^T h0 + b1); acc init = b1 ----
            #pragma unroll
            for (int nh = 0; nh < 2; ++nh) {
                f32x4 acc[2][2];
                #pragma unroll
                for (int mt = 0; mt < 2; ++mt)
                  #pragma unroll
                  for (int nt = 0; nt < 2; ++nt) acc[mt][nt] = b1v[mt];
                #pragma unroll
                for (int ks = 0; ks < 4; ++ks) {
                    h16x8 bf[2];
                    #pragma unroll
                    for (int nt = 0; nt < 2; ++nt) {
                        const int row = nh * 32 + nt * 16 + l16;
                        bf[nt] = *(const h16x8*)(&sHa[sh_idx(row, ks * 4 + q)]);
                    }
                    #pragma unroll
                    for (int mt = 0; mt < 2; ++mt)
                      #pragma unroll
                      for (int nt = 0; nt < 2; ++nt)
                        acc[mt][nt] = __builtin_amdgcn_mfma_f32_16x16x32_f16(
                            w1f[ks][mt], bf[nt], acc[mt][nt], 0, 0, 0);
                }
                #pragma unroll
                for (int mt = 0; mt < 2; ++mt)
                  #pragma unroll
                  for (int nt = 0; nt < 2; ++nt) {
                    const int row = nh * 32 + nt * 16 + l16;
                    const int blk = (fb >> 3) + mt * 2 + (q >> 1);
                    const int idx = sh_idx(row, blk) + (q & 1) * 4;
                    uint2 pk;
                    pk.x = pklr(acc[mt][nt][0], acc[mt][nt][1]);
                    pk.y = pklr(acc[mt][nt][2], acc[mt][nt][3]);
                    *reinterpret_cast<uint2*>(&sHb[idx]) = pk;
                  }
            }
            __syncthreads();   // B3: h1 + sIn(i+1) ready

            // ---- Layer 2 (R4 orientation): A=h1 (m=batch), B=W2 (n=feature) ----
            {
                f32x4 acc2[2];
                acc2[0] = z4; acc2[1] = z4;
                #pragma unroll
                for (int ks = 0; ks < 4; ++ks) {
                    #pragma unroll
                    for (int mt = 0; mt < 2; ++mt) {
                        const int row = l2m + 16 * mt + l16;
                        const h16x8 a2 = *(const h16x8*)(&sHb[sh_idx(row, ks * 4 + q)]);
                        acc2[mt] = __builtin_amdgcn_mfma_f32_16x16x32_f16(
                            a2, w2f[ks], acc2[mt], 0, 0, 0);
                    }
                }
                #pragma unroll
                for (int mt = 0; mt < 2; ++mt)
                  #pragma unroll
                  for (int r = 0; r < 4; ++r) {
                    const float a = acc2[mt][r];      // b2 deferred
                    sa[mt][r] += a;
                    sq[mt][r] = fmaf(a, a, sq[mt][r]);
                  }
            }
        }

        // ---- Epilogue for this bt: sum = sa + 8b; sum(p^2) = sq + 2b*sa + 8b^2
        #pragma unroll
        for (int mt = 0; mt < 2; ++mt)
          #pragma unroll
          for (int r = 0; r < 4; ++r) {
            const int row = l2m + 16 * mt + q * 4 + r;   // batch row (C: row=quad*4+r)
            const int col = l2n + l16;                   // feature
            const size_t o = ((size_t)j * NB + b0 + row) * DS + col;
            const float b  = b2s;
            const float s  = sa[mt][r] + 8.f * b;
            const float s2 = sq[mt][r] + 2.f * b * sa[mt][r] + 8.f * b * b;
            out[o] = s * 0.125f + states[o];
            out[(size_t)NE * NB * DS + o] = (s2 - s * s * 0.125f) * (1.0f / 7.0f);
          }
    }
}

extern "C" void kernel_launch(void* const* d_in, const int* in_sizes, int n_in,
                              void* d_out, int out_size, void* d_ws, size_t ws_size,
                              hipStream_t stream) {
    (void)in_sizes; (void)n_in; (void)d_ws; (void)ws_size; (void)out_size;
    const float* states  = (const float*)d_in[0];
    const float* actions = (const float*)d_in[1];
    const float* W0 = (const float*)d_in[2];
    const float* b0 = (const float*)d_in[3];
    const float* W1 = (const float*)d_in[4];
    const float* b1 = (const float*)d_in[5];
    const float* W2 = (const float*)d_in[6];
    const float* b2 = (const float*)d_in[7];
    float* out = (float*)d_out;
    dim3 grid(8 * NSLOT);   // 768 persistent blocks = 3/CU, one generation
    ens_mlp_kernel<<<grid, dim3(256), 0, stream>>>(states, actions, W0, b0, W1, b1, W2, b2, out);
}